// Round 6
// baseline (154.345 us; speedup 1.0000x reference)
//
#include <hip/hip_runtime.h>

// Density-Aware Chamfer Loss, B=8, N=M=4096, fp32.
// Round 6: strip-granularity dedup. Blocks own a 128-pt row strip and sweep
// col tiles with row accumulators resident in registers; col partials flush
// once per 128x128 tile (shfl + atomic, no in-loop barriers).
//   cross:   1 enumeration, dual mins: ~6.75 slots/pair (serves 2 outputs)
//   density: upper-triangle symmetric: ~10.75 slots/pair (serves 2 outputs)

#define NPTS 4096
#define NB   8
#define TS   128
#define TPB  256
#define NT   32
#define BIGF 3.4e38f

#define DENS_BLKS  512   // 2 clouds * 8 batches * 16 strip-pairs * 2 halves
#define CROSS_BLKS 256   // 8 batches * 32 strips

// unpack 8 consecutive xyz points (6 float4) from LDS into register arrays
__device__ __forceinline__ void unpack8(const float4* s4, int base,
                                        float (&X)[8], float (&Y)[8], float (&Z)[8])
{
    float4 A = s4[base+0], B = s4[base+1], C = s4[base+2];
    float4 D = s4[base+3], E = s4[base+4], F = s4[base+5];
    X[0]=A.x; Y[0]=A.y; Z[0]=A.z;  X[1]=A.w; Y[1]=B.x; Z[1]=B.y;
    X[2]=B.z; Y[2]=B.w; Z[2]=C.x;  X[3]=C.y; Y[3]=C.z; Z[3]=C.w;
    X[4]=D.x; Y[4]=D.y; Z[4]=D.z;  X[5]=D.w; Y[5]=E.x; Z[5]=E.y;
    X[6]=E.z; Y[6]=E.w; Z[6]=F.x;  X[7]=F.y; Y[7]=F.z; Z[7]=F.w;
}

// g < 32768: minG2P[g] = +inf bits; g in [32768,98304): dens[g-32768] = 0
__global__ __launch_bounds__(256) void dacl_init(int* __restrict__ minG2P,
                                                 float* __restrict__ dens)
{
    const int g = blockIdx.x * 256 + threadIdx.x;
    if (g < 32768) minG2P[g] = 0x7F800000;
    else           dens[g - 32768] = 0.0f;
}

__global__ __launch_bounds__(TPB) void dacl_pairs(
    const float* __restrict__ pred, const float* __restrict__ gt,
    const float* __restrict__ bwp,  const float* __restrict__ bwg,
    float* __restrict__ minP2G, int* __restrict__ minG2P,
    float* __restrict__ densP,  float* __restrict__ densG)
{
    __shared__ float4 sCol[1632];      // 25.5 KB: up to 17 col tiles
    __shared__ float4 sRowA[96], sRowB[96];
    float* sRed = (float*)sCol;        // aliased AFTER final barrier (cross)

    const int tid  = threadIdx.x;
    const int ty   = tid & 15;         // row octet (lane bits 0..3)
    const int tx   = tid >> 4;         // col octet
    const int wave = tid >> 6;
    const int lane = tid & 63;
    const int bid  = blockIdx.x;

    if (bid < DENS_BLKS) {
        // ============ density: strip-pair {u, 31-u}, one col half ============
        const int half = bid & 1;
        const int u    = (bid >> 1) & 15;
        const int b    = (bid >> 5) & 7;
        const int cl   = bid >> 8;

        const float* __restrict__ P = cl ? gt : pred;
        float* __restrict__ D = cl ? densG : densP;
        const float bw = cl ? bwg[0] : bwp[0];
        const float sc = sqrtf(0.5f / (bw*bw*0.6931471805599453f)); // exp2 prescale

        const int n0  = 32 - u;                // seg A step count (RT=u)
        const int lo  = half ? 17 : 0;
        const int hi  = half ? 33 : 17;
        const int nst = hi - lo;               // 17 or 16
        int nA = n0 - lo; if (nA < 0) nA = 0; if (nA > nst) nA = nst;
        const int tA0 = u + lo;                // seg A first col tile
        const int tB0 = 31 - u;                // seg B first col tile (diag)

        const float4* cb4 = (const float4*)(P + (size_t)b*NPTS*3);

        if (tid < 96) {
            float4 v = cb4[u*96 + tid];
            v.x*=sc; v.y*=sc; v.z*=sc; v.w*=sc;  sRowA[tid] = v;
        } else if (tid < 192) {
            float4 v = cb4[(31-u)*96 + (tid-96)];
            v.x*=sc; v.y*=sc; v.z*=sc; v.w*=sc;  sRowB[tid-96] = v;
        }
        const int nA96 = nA * 96;
        for (int i = tid; i < nst*96; i += TPB) {
            float4 v = (i < nA96) ? cb4[tA0*96 + i] : cb4[tB0*96 + (i - nA96)];
            v.x*=sc; v.y*=sc; v.z*=sc; v.w*=sc;  sCol[i] = v;
        }
        __syncthreads();

        float rx[8], ry[8], rz[8], nrr[8], racc[8];
        const bool startA = (lo < n0);
        unpack8(startA ? sRowA : sRowB, ty*6, rx, ry, rz);
        #pragma unroll
        for (int r = 0; r < 8; ++r) {
            nrr[r]  = -fmaf(rx[r],rx[r], fmaf(ry[r],ry[r], rz[r]*rz[r]));
            racc[r] = 0.0f;
        }
        int curRT = startA ? u : 31-u;

        auto flushRows = [&](int RTf) {
            #pragma unroll
            for (int r = 0; r < 8; ++r) {
                float v = racc[r];
                v += __shfl_xor(v, 16, 64);
                v += __shfl_xor(v, 32, 64);
                if ((tx & 3) == 0)
                    atomicAdd(&D[b*NPTS + RTf*TS + ty*8 + r], v);
            }
        };

        for (int s = lo; s < hi; ++s) {
            const int t    = s - lo;
            const bool segA = (s < n0);
            const int RT   = segA ? u : 31-u;
            const int TV   = segA ? u + s : (31-u) + (s - n0);

            if (RT != curRT) {          // happens at most once (u -> 31-u)
                flushRows(curRT);
                unpack8(sRowB, ty*6, rx, ry, rz);
                #pragma unroll
                for (int r = 0; r < 8; ++r) {
                    nrr[r]  = -fmaf(rx[r],rx[r], fmaf(ry[r],ry[r], rz[r]*rz[r]));
                    racc[r] = 0.0f;
                }
                curRT = RT;
            }

            float cx[8], cy[8], cz[8];
            unpack8(sCol, t*96 + tx*6, cx, cy, cz);

            if (s == 0 || s == n0) {
                // diagonal tile: full 128x128, rows only (self incl., exp2(0)=1)
                #pragma unroll
                for (int c = 0; c < 8; ++c) {
                    const float ax = 2.0f*cx[c], ay = 2.0f*cy[c], az = 2.0f*cz[c];
                    const float ncc = fmaf(-cx[c],cx[c],
                                      fmaf(-cy[c],cy[c], -cz[c]*cz[c]));
                    #pragma unroll
                    for (int r = 0; r < 8; ++r) {
                        float e = fmaf(ax, rx[r], ncc);
                        e = fmaf(ay, ry[r], e);
                        e = fmaf(az, rz[r], e);
                        racc[r] += __builtin_amdgcn_exp2f(e + nrr[r]);
                    }
                }
            } else {
                float cacc[8];
                #pragma unroll
                for (int c = 0; c < 8; ++c) cacc[c] = 0.0f;
                #pragma unroll
                for (int c = 0; c < 8; ++c) {
                    const float ax = 2.0f*cx[c], ay = 2.0f*cy[c], az = 2.0f*cz[c];
                    const float ncc = fmaf(-cx[c],cx[c],
                                      fmaf(-cy[c],cy[c], -cz[c]*cz[c]));
                    #pragma unroll
                    for (int r = 0; r < 8; ++r) {
                        float e = fmaf(ax, rx[r], ncc);
                        e = fmaf(ay, ry[r], e);
                        e = fmaf(az, rz[r], e);
                        const float k = __builtin_amdgcn_exp2f(e + nrr[r]);
                        racc[r] += k;
                        cacc[c] += k;
                    }
                }
                // col flush: complete over this strip's 128 rows, one atomic
                #pragma unroll
                for (int c = 0; c < 8; ++c) {
                    float v = cacc[c];
                    v += __shfl_xor(v, 1, 64);
                    v += __shfl_xor(v, 2, 64);
                    v += __shfl_xor(v, 4, 64);
                    v += __shfl_xor(v, 8, 64);
                    if (ty == 0)
                        atomicAdd(&D[b*NPTS + TV*TS + tx*8 + c], v);
                }
            }
        }
        flushRows(curRT);
    } else {
        // ============ cross: pred strip I x all 32 gt tiles, dual mins =======
        const int cb = bid - DENS_BLKS;
        const int b  = cb >> 5;
        const int I  = cb & 31;

        const float4* pb4 = (const float4*)(pred + (size_t)b*NPTS*3);
        const float4* gb4 = (const float4*)(gt   + (size_t)b*NPTS*3);
        if (tid < 96) sRowA[tid] = pb4[I*96 + tid];

        float rx[8], ry[8], rz[8], rr[8], rmin[8];
        #pragma unroll
        for (int r = 0; r < 8; ++r) rmin[r] = BIGF;

        for (int ph = 0; ph < 2; ++ph) {
            __syncthreads();                         // sCol reuse guard
            #pragma unroll
            for (int i = 0; i < 6; ++i)
                sCol[tid + i*TPB] = gb4[ph*1536 + tid + i*TPB];
            __syncthreads();
            if (ph == 0) {
                unpack8(sRowA, ty*6, rx, ry, rz);
                #pragma unroll
                for (int r = 0; r < 8; ++r)
                    rr[r] = fmaf(rx[r],rx[r], fmaf(ry[r],ry[r], rz[r]*rz[r]));
            }
            for (int t = 0; t < 16; ++t) {
                float cx[8], cy[8], cz[8], cmin[8];
                unpack8(sCol, t*96 + tx*6, cx, cy, cz);
                #pragma unroll
                for (int c = 0; c < 8; ++c) cmin[c] = BIGF;
                #pragma unroll
                for (int c = 0; c < 8; ++c) {
                    const float ax = -2.0f*cx[c], ay = -2.0f*cy[c], az = -2.0f*cz[c];
                    const float cc = fmaf(cx[c],cx[c],
                                     fmaf(cy[c],cy[c], cz[c]*cz[c]));
                    #pragma unroll
                    for (int r = 0; r < 8; ++r) {
                        float tv = fmaf(ax, rx[r], cc);
                        tv = fmaf(ay, ry[r], tv);
                        tv = fmaf(az, rz[r], tv);
                        rmin[r] = fminf(rmin[r], tv);          // +rr at end
                        cmin[c] = fminf(cmin[c], tv + rr[r]);  // true d^2
                    }
                }
                // col-min flush: complete over strip rows, exact atomicMin
                #pragma unroll
                for (int c = 0; c < 8; ++c) {
                    float v = fmaxf(cmin[c], 0.0f);
                    v = fminf(v, __shfl_xor(v, 1, 64));
                    v = fminf(v, __shfl_xor(v, 2, 64));
                    v = fminf(v, __shfl_xor(v, 4, 64));
                    v = fminf(v, __shfl_xor(v, 8, 64));
                    if (ty == 0)
                        atomicMin(&minG2P[b*NPTS + (ph*16+t)*TS + tx*8 + c],
                                  __float_as_int(v));
                }
            }
        }
        // row mins: exclusive ownership -> plain store via sRed combine
        float vv[8];
        #pragma unroll
        for (int r = 0; r < 8; ++r) {
            float v = fmaxf(rmin[r] + rr[r], 0.0f);
            v = fminf(v, __shfl_xor(v, 16, 64));
            v = fminf(v, __shfl_xor(v, 32, 64));
            vv[r] = v;
        }
        __syncthreads();                    // sCol reads done -> alias as sRed
        if (wave > 0 && lane < 16) {
            #pragma unroll
            for (int r = 0; r < 8; ++r) sRed[(wave-1)*128 + lane*8 + r] = vv[r];
        }
        __syncthreads();
        if (wave == 0 && lane < 16) {
            #pragma unroll
            for (int r = 0; r < 8; ++r) {
                const int o = lane*8 + r;
                minP2G[b*NPTS + I*TS + o] =
                    fminf(fminf(vv[r], sRed[o]),
                          fminf(sRed[128+o], sRed[256+o]));
            }
        }
    }
}

__global__ __launch_bounds__(256) void dacl_combine(
    const float* __restrict__ minP2G, const int* __restrict__ minG2P,
    const float* __restrict__ densP, const float* __restrict__ densG,
    float* __restrict__ bsum)
{
    const int g   = blockIdx.x * 256 + threadIdx.x;  // [0, 65536)
    const int dir = g >> 15;
    const int idx = g & 32767;
    const float m  = dir ? __int_as_float(minG2P[idx]) : minP2G[idx];
    const float dn = dir ? densG[idx] : densP[idx];
    float val = m / (dn * (1.0f/4095.0f) + 1e-6f) * (1.0f/32768.0f);

    #pragma unroll
    for (int off = 32; off; off >>= 1) val += __shfl_down(val, off);
    __shared__ float sm[4];
    const int lane = threadIdx.x & 63, wid = threadIdx.x >> 6;
    if (lane == 0) sm[wid] = val;
    __syncthreads();
    if (threadIdx.x == 0) bsum[blockIdx.x] = (sm[0] + sm[1]) + (sm[2] + sm[3]);
}

__global__ __launch_bounds__(256) void dacl_final(
    const float* __restrict__ bsum, float* __restrict__ out)
{
    float v = bsum[threadIdx.x];
    #pragma unroll
    for (int off = 32; off; off >>= 1) v += __shfl_down(v, off);
    __shared__ float sm[4];
    const int lane = threadIdx.x & 63, wid = threadIdx.x >> 6;
    if (lane == 0) sm[wid] = v;
    __syncthreads();
    if (threadIdx.x == 0) out[0] = (sm[0] + sm[1]) + (sm[2] + sm[3]);
}

extern "C" void kernel_launch(void* const* d_in, const int* in_sizes, int n_in,
                              void* d_out, int out_size, void* d_ws, size_t ws_size,
                              hipStream_t stream)
{
    const float* pred = (const float*)d_in[0];
    const float* gt   = (const float*)d_in[1];
    const float* bwp  = (const float*)d_in[2];
    const float* bwg  = (const float*)d_in[3];

    float* minP2G = (float*)d_ws;                 // [NB*NPTS]
    int*   minG2P = (int*)(minP2G + NB*NPTS);     // [NB*NPTS]
    float* densP  = (float*)(minG2P + NB*NPTS);   // [NB*NPTS]
    float* densG  = densP + NB*NPTS;              // [NB*NPTS]
    float* bsum   = densG + NB*NPTS;              // [256]

    dacl_init<<<(3*NB*NPTS)/256, 256, 0, stream>>>(minG2P, densP);
    dacl_pairs<<<DENS_BLKS + CROSS_BLKS, TPB, 0, stream>>>(
        pred, gt, bwp, bwg, minP2G, minG2P, densP, densG);
    dacl_combine<<<(2*NB*NPTS)/256, 256, 0, stream>>>(minP2G, minG2P, densP, densG, bsum);
    dacl_final<<<1, 256, 0, stream>>>(bsum, (float*)d_out);
}

// Round 7
// 115.857 us; speedup vs baseline: 1.3322x; 1.3322x over previous
//
#include <hip/hip_runtime.h>

// Density-Aware Chamfer Loss, B=8, N=M=4096, fp32.
// Round 7: strip-dedup (round 6 math) + XCD-SLICED accumulators.
// Diagnosis: rounds 2/3/5/6 were atomic-writeback-bound (dur ~= WRITE_SIZE/BW):
// atomics from all 8 XCDs to one 512KB region bounce lines through HBM.
// Fix: 8 slices indexed by blockIdx&7 (~XCD id under round-robin dispatch) ->
// atomics stay in the local XCD L2; combine kernel reduces slices.

#define NPTS 4096
#define NB   8
#define TS   128
#define TPB  256
#define NT   32
#define BIGF 3.4e38f

#define DENS_BLKS  512   // cl(2) * b(8) * strip-pair u(16) * half(2)
#define CROSS_BLKS 512   // b(8) * strip I(32) * phase(2)
#define SLICES 8
#define PTSTOT (NB*NPTS)     // 32768

// unpack 8 consecutive xyz points (6 float4) from LDS into register arrays
__device__ __forceinline__ void unpack8(const float4* s4, int base,
                                        float (&X)[8], float (&Y)[8], float (&Z)[8])
{
    float4 A = s4[base+0], B = s4[base+1], C = s4[base+2];
    float4 D = s4[base+3], E = s4[base+4], F = s4[base+5];
    X[0]=A.x; Y[0]=A.y; Z[0]=A.z;  X[1]=A.w; Y[1]=B.x; Z[1]=B.y;
    X[2]=B.z; Y[2]=B.w; Z[2]=C.x;  X[3]=C.y; Y[3]=C.z; Z[3]=C.w;
    X[4]=D.x; Y[4]=D.y; Z[4]=D.z;  X[5]=D.w; Y[5]=E.x; Z[5]=E.y;
    X[6]=E.z; Y[6]=E.w; Z[6]=F.x;  X[7]=F.y; Y[7]=F.z; Z[7]=F.w;
}

// Slice-aware init: block bid&7 == s pre-touches slice s so lines are born
// in the XCD that will atomically update them.
__global__ __launch_bounds__(256) void dacl_init(
    int* __restrict__ minG2P_s, float* __restrict__ densP_s,
    float* __restrict__ densG_s)
{
    const int bid = blockIdx.x;           // [0, 3072)
    const int s   = bid & 7;
    const int j   = bid >> 3;             // [0, 384)
    const int arr = j >> 7;               // 0,1,2
    const int k   = j & 127;
    const int off = s * PTSTOT + k * 256 + threadIdx.x;
    if (arr == 0)      minG2P_s[off] = 0x7F800000;
    else if (arr == 1) densP_s[off]  = 0.0f;
    else               densG_s[off]  = 0.0f;
}

__global__ __launch_bounds__(TPB) void dacl_pairs(
    const float* __restrict__ pred, const float* __restrict__ gt,
    const float* __restrict__ bwp,  const float* __restrict__ bwg,
    float* __restrict__ minP2G_h, int* __restrict__ minG2P_s,
    float* __restrict__ densP_s,  float* __restrict__ densG_s)
{
    __shared__ float4 sCol[1632];      // 25.5 KB: up to 17 col tiles
    __shared__ float4 sRowA[96], sRowB[96];
    float* sRed = (float*)sCol;        // aliased only AFTER final barrier

    const int tid   = threadIdx.x;
    const int ty    = tid & 15;        // row octet (lane bits 0..3)
    const int tx    = tid >> 4;        // col octet
    const int wave  = tid >> 6;
    const int lane  = tid & 63;
    const int bid   = blockIdx.x;
    const int slice = bid & 7;         // ~XCD id under round-robin dispatch

    if (bid < DENS_BLKS) {
        // ============ density: strip-pair {u, 31-u}, one col half ============
        const int half = bid & 1;
        const int u    = (bid >> 1) & 15;
        const int b    = (bid >> 5) & 7;
        const int cl   = bid >> 8;

        const float* __restrict__ P = cl ? gt : pred;
        float* __restrict__ D = (cl ? densG_s : densP_s)
                                + (size_t)slice * PTSTOT + b * NPTS;
        const float bw = cl ? bwg[0] : bwp[0];
        const float sc = sqrtf(0.5f / (bw*bw*0.6931471805599453f)); // exp2 prescale

        const int n0  = 32 - u;                // seg A step count (RT=u)
        const int lo  = half ? 17 : 0;
        const int hi  = half ? 33 : 17;
        const int nst = hi - lo;               // 17 or 16
        int nA = n0 - lo; if (nA < 0) nA = 0; if (nA > nst) nA = nst;
        const int tA0 = u + lo;                // seg A first col tile
        const int tB0 = 31 - u;                // seg B first col tile (diag)

        const float4* cb4 = (const float4*)(P + (size_t)b*NPTS*3);

        if (tid < 96) {
            float4 v = cb4[u*96 + tid];
            v.x*=sc; v.y*=sc; v.z*=sc; v.w*=sc;  sRowA[tid] = v;
        } else if (tid < 192) {
            float4 v = cb4[(31-u)*96 + (tid-96)];
            v.x*=sc; v.y*=sc; v.z*=sc; v.w*=sc;  sRowB[tid-96] = v;
        }
        const int nA96 = nA * 96;
        for (int i = tid; i < nst*96; i += TPB) {
            float4 v = (i < nA96) ? cb4[tA0*96 + i] : cb4[tB0*96 + (i - nA96)];
            v.x*=sc; v.y*=sc; v.z*=sc; v.w*=sc;  sCol[i] = v;
        }
        __syncthreads();

        float rx[8], ry[8], rz[8], nrr[8], racc[8];
        const bool startA = (lo < n0);
        unpack8(startA ? sRowA : sRowB, ty*6, rx, ry, rz);
        #pragma unroll
        for (int r = 0; r < 8; ++r) {
            nrr[r]  = -fmaf(rx[r],rx[r], fmaf(ry[r],ry[r], rz[r]*rz[r]));
            racc[r] = 0.0f;
        }
        int curRT = startA ? u : 31-u;

        auto flushRows = [&](int RTf) {
            #pragma unroll
            for (int r = 0; r < 8; ++r) {
                float v = racc[r];
                v += __shfl_xor(v, 16, 64);
                v += __shfl_xor(v, 32, 64);
                if ((tx & 3) == 0)
                    atomicAdd(&D[RTf*TS + ty*8 + r], v);   // L2-local (sliced)
            }
        };

        for (int s = lo; s < hi; ++s) {
            const int t     = s - lo;
            const bool segA = (s < n0);
            const int RT    = segA ? u : 31-u;
            const int TV    = segA ? u + s : (31-u) + (s - n0);

            if (RT != curRT) {          // at most once (u -> 31-u)
                flushRows(curRT);
                unpack8(sRowB, ty*6, rx, ry, rz);
                #pragma unroll
                for (int r = 0; r < 8; ++r) {
                    nrr[r]  = -fmaf(rx[r],rx[r], fmaf(ry[r],ry[r], rz[r]*rz[r]));
                    racc[r] = 0.0f;
                }
                curRT = RT;
            }

            float cx[8], cy[8], cz[8];
            unpack8(sCol, t*96 + tx*6, cx, cy, cz);

            if (s == 0 || s == n0) {
                // diagonal tile: rows only (self incl., exp2(0)=1)
                #pragma unroll
                for (int c = 0; c < 8; ++c) {
                    const float ax = 2.0f*cx[c], ay = 2.0f*cy[c], az = 2.0f*cz[c];
                    const float ncc = fmaf(-cx[c],cx[c],
                                      fmaf(-cy[c],cy[c], -cz[c]*cz[c]));
                    #pragma unroll
                    for (int r = 0; r < 8; ++r) {
                        float e = fmaf(ax, rx[r], ncc);
                        e = fmaf(ay, ry[r], e);
                        e = fmaf(az, rz[r], e);
                        racc[r] += __builtin_amdgcn_exp2f(e + nrr[r]);
                    }
                }
            } else {
                float cacc[8];
                #pragma unroll
                for (int c = 0; c < 8; ++c) cacc[c] = 0.0f;
                #pragma unroll
                for (int c = 0; c < 8; ++c) {
                    const float ax = 2.0f*cx[c], ay = 2.0f*cy[c], az = 2.0f*cz[c];
                    const float ncc = fmaf(-cx[c],cx[c],
                                      fmaf(-cy[c],cy[c], -cz[c]*cz[c]));
                    #pragma unroll
                    for (int r = 0; r < 8; ++r) {
                        float e = fmaf(ax, rx[r], ncc);
                        e = fmaf(ay, ry[r], e);
                        e = fmaf(az, rz[r], e);
                        const float k = __builtin_amdgcn_exp2f(e + nrr[r]);
                        racc[r] += k;
                        cacc[c] += k;
                    }
                }
                // col flush: complete over this strip's 128 rows, sliced atomic
                #pragma unroll
                for (int c = 0; c < 8; ++c) {
                    float v = cacc[c];
                    v += __shfl_xor(v, 1, 64);
                    v += __shfl_xor(v, 2, 64);
                    v += __shfl_xor(v, 4, 64);
                    v += __shfl_xor(v, 8, 64);
                    if (ty == 0)
                        atomicAdd(&D[TV*TS + tx*8 + c], v);
                }
            }
        }
        flushRows(curRT);
    } else {
        // ============ cross: pred strip I x 16 gt tiles (one phase) ==========
        const int cb   = bid - DENS_BLKS;
        const int b    = cb >> 6;
        const int rest = cb & 63;
        const int I    = rest >> 1;
        const int ph   = rest & 1;

        const float4* pb4 = (const float4*)(pred + (size_t)b*NPTS*3);
        const float4* gb4 = (const float4*)(gt   + (size_t)b*NPTS*3);
        if (tid < 96) sRowA[tid] = pb4[I*96 + tid];
        #pragma unroll
        for (int i = 0; i < 6; ++i)
            sCol[tid + i*TPB] = gb4[ph*1536 + tid + i*TPB];
        __syncthreads();

        float rx[8], ry[8], rz[8], rr[8], rmin[8];
        unpack8(sRowA, ty*6, rx, ry, rz);
        #pragma unroll
        for (int r = 0; r < 8; ++r) {
            rr[r]   = fmaf(rx[r],rx[r], fmaf(ry[r],ry[r], rz[r]*rz[r]));
            rmin[r] = BIGF;
        }
        int* mg = minG2P_s + (size_t)slice * PTSTOT + b * NPTS;

        for (int t = 0; t < 16; ++t) {
            float cx[8], cy[8], cz[8], cmin[8];
            unpack8(sCol, t*96 + tx*6, cx, cy, cz);
            #pragma unroll
            for (int c = 0; c < 8; ++c) cmin[c] = BIGF;
            #pragma unroll
            for (int c = 0; c < 8; ++c) {
                const float ax = -2.0f*cx[c], ay = -2.0f*cy[c], az = -2.0f*cz[c];
                const float cc = fmaf(cx[c],cx[c], fmaf(cy[c],cy[c], cz[c]*cz[c]));
                #pragma unroll
                for (int r = 0; r < 8; ++r) {
                    float tv = fmaf(ax, rx[r], cc);
                    tv = fmaf(ay, ry[r], tv);
                    tv = fmaf(az, rz[r], tv);
                    rmin[r] = fminf(rmin[r], tv);          // +rr at end
                    cmin[c] = fminf(cmin[c], tv + rr[r]);  // true d^2
                }
            }
            // col-min flush: exact (clamped >=0 -> int cmp == float cmp)
            #pragma unroll
            for (int c = 0; c < 8; ++c) {
                float v = fmaxf(cmin[c], 0.0f);
                v = fminf(v, __shfl_xor(v, 1, 64));
                v = fminf(v, __shfl_xor(v, 2, 64));
                v = fminf(v, __shfl_xor(v, 4, 64));
                v = fminf(v, __shfl_xor(v, 8, 64));
                if (ty == 0)
                    atomicMin(&mg[(ph*16+t)*TS + tx*8 + c], __float_as_int(v));
            }
        }
        // row-min partials: exclusive (b,I,ph) ownership -> plain store
        float vv[8];
        #pragma unroll
        for (int r = 0; r < 8; ++r) {
            float v = fmaxf(rmin[r] + rr[r], 0.0f);
            v = fminf(v, __shfl_xor(v, 16, 64));
            v = fminf(v, __shfl_xor(v, 32, 64));
            vv[r] = v;
        }
        __syncthreads();                    // sCol reads done -> alias as sRed
        if (wave > 0 && lane < 16) {
            #pragma unroll
            for (int r = 0; r < 8; ++r) sRed[(wave-1)*128 + lane*8 + r] = vv[r];
        }
        __syncthreads();
        if (wave == 0 && lane < 16) {
            #pragma unroll
            for (int r = 0; r < 8; ++r) {
                const int o = lane*8 + r;
                minP2G_h[ph*PTSTOT + b*NPTS + I*TS + o] =
                    fminf(fminf(vv[r], sRed[o]),
                          fminf(sRed[128+o], sRed[256+o]));
            }
        }
    }
}

__global__ __launch_bounds__(256) void dacl_combine(
    const float* __restrict__ minP2G_h, const int* __restrict__ minG2P_s,
    const float* __restrict__ densP_s,  const float* __restrict__ densG_s,
    float* __restrict__ bsum)
{
    const int g   = blockIdx.x * 256 + threadIdx.x;  // [0, 65536)
    const int dir = g >> 15;
    const int idx = g & 32767;
    float m, dn = 0.0f;
    if (dir == 0) {
        m = fminf(minP2G_h[idx], minP2G_h[PTSTOT + idx]);
        #pragma unroll
        for (int s = 0; s < SLICES; ++s) dn += densP_s[s*PTSTOT + idx];
    } else {
        int mi = 0x7F800000;
        #pragma unroll
        for (int s = 0; s < SLICES; ++s) mi = min(mi, minG2P_s[s*PTSTOT + idx]);
        m = __int_as_float(mi);
        #pragma unroll
        for (int s = 0; s < SLICES; ++s) dn += densG_s[s*PTSTOT + idx];
    }
    float val = m / (dn * (1.0f/4095.0f) + 1e-6f) * (1.0f/32768.0f);

    #pragma unroll
    for (int off = 32; off; off >>= 1) val += __shfl_down(val, off);
    __shared__ float sm[4];
    const int lane = threadIdx.x & 63, wid = threadIdx.x >> 6;
    if (lane == 0) sm[wid] = val;
    __syncthreads();
    if (threadIdx.x == 0) bsum[blockIdx.x] = (sm[0] + sm[1]) + (sm[2] + sm[3]);
}

__global__ __launch_bounds__(256) void dacl_final(
    const float* __restrict__ bsum, float* __restrict__ out)
{
    float v = bsum[threadIdx.x];
    #pragma unroll
    for (int off = 32; off; off >>= 1) v += __shfl_down(v, off);
    __shared__ float sm[4];
    const int lane = threadIdx.x & 63, wid = threadIdx.x >> 6;
    if (lane == 0) sm[wid] = v;
    __syncthreads();
    if (threadIdx.x == 0) out[0] = (sm[0] + sm[1]) + (sm[2] + sm[3]);
}

extern "C" void kernel_launch(void* const* d_in, const int* in_sizes, int n_in,
                              void* d_out, int out_size, void* d_ws, size_t ws_size,
                              hipStream_t stream)
{
    const float* pred = (const float*)d_in[0];
    const float* gt   = (const float*)d_in[1];
    const float* bwp  = (const float*)d_in[2];
    const float* bwg  = (const float*)d_in[3];

    float* minP2G_h = (float*)d_ws;                        // [2][32768]
    int*   minG2P_s = (int*)(minP2G_h + 2*PTSTOT);         // [8][32768]
    float* densP_s  = (float*)(minG2P_s + SLICES*PTSTOT);  // [8][32768]
    float* densG_s  = densP_s + SLICES*PTSTOT;             // [8][32768]
    float* bsum     = densG_s + SLICES*PTSTOT;             // [256]

    dacl_init<<<3072, 256, 0, stream>>>(minG2P_s, densP_s, densG_s);
    dacl_pairs<<<DENS_BLKS + CROSS_BLKS, TPB, 0, stream>>>(
        pred, gt, bwp, bwg, minP2G_h, minG2P_s, densP_s, densG_s);
    dacl_combine<<<256, 256, 0, stream>>>(minP2G_h, minG2P_s, densP_s, densG_s, bsum);
    dacl_final<<<1, 256, 0, stream>>>(bsum, (float*)d_out);
}

// Round 8
// 93.552 us; speedup vs baseline: 1.6498x; 1.2384x over previous
//
#include <hip/hip_runtime.h>

// Density-Aware Chamfer Loss, B=8, N=M=4096, fp32.
// Round 8: dedup'd enumeration with ZERO atomics. All reductions go through
// exclusively-owned partial arrays (plain coalesced stores) + a combine pass.
// Diagnosis r2/3/5/6/7: atomics execute past L2 on gfx950 -> WRITE_SIZE ~
// atomic-count * 32B (76-131MB), dur ~= WRITE_SIZE/BW. Round 4 (no atomics,
// 94% VALUBusy) is the structural template; this round adds the 2x work cut.

#define NPTS 4096
#define NB   8
#define TS   128
#define TPB  256
#define NT   32
#define BIGF 3.4e38f

#define DENS_BLKS  512       // cl(2) * b(8) * strip-pair u(16) * half(2)
#define CROSS_BLKS 512       // b(8) * strip I(32) * phase(2)
#define PTSTOT (NB*NPTS)     // 32768
#define TRIVEC 496           // sum_{T} T  (T=0..31): packed (RT<TV) vectors

// unpack 8 consecutive xyz points (6 float4) from LDS into register arrays
__device__ __forceinline__ void unpack8(const float4* s4, int base,
                                        float (&X)[8], float (&Y)[8], float (&Z)[8])
{
    float4 A = s4[base+0], B = s4[base+1], C = s4[base+2];
    float4 D = s4[base+3], E = s4[base+4], F = s4[base+5];
    X[0]=A.x; Y[0]=A.y; Z[0]=A.z;  X[1]=A.w; Y[1]=B.x; Z[1]=B.y;
    X[2]=B.z; Y[2]=B.w; Z[2]=C.x;  X[3]=C.y; Y[3]=C.z; Z[3]=C.w;
    X[4]=D.x; Y[4]=D.y; Z[4]=D.z;  X[5]=D.w; Y[5]=E.x; Z[5]=E.y;
    X[6]=E.z; Y[6]=E.w; Z[6]=F.x;  X[7]=F.y; Y[7]=F.z; Z[7]=F.w;
}

__global__ __launch_bounds__(TPB) void dacl_pairs(
    const float* __restrict__ pred, const float* __restrict__ gt,
    const float* __restrict__ bwp,  const float* __restrict__ bwg,
    float* __restrict__ minP2Gp,   // [8 = ph*4+wave][b][4096]
    float* __restrict__ minG2Pp,   // [I=32][b][4096]
    float* __restrict__ densCol,   // [(cl*8+b)][TRIVEC][128]  (tri-packed)
    float* __restrict__ densRow)   // [8 = h*4+wave][cl][b][4096]
{
    __shared__ float4 sCol[1632];      // 25.5 KB: up to 17 col tiles
    __shared__ float4 sRowA[96], sRowB[96];

    const int tid  = threadIdx.x;
    const int ty   = tid & 15;         // row octet (lane bits 0..3)
    const int tx   = tid >> 4;         // col octet
    const int wave = tid >> 6;
    const int bid  = blockIdx.x;

    if (bid < DENS_BLKS) {
        // ============ density: strip-pair {u, 31-u}, one col half ============
        const int half = bid & 1;
        const int u    = (bid >> 1) & 15;
        const int b    = (bid >> 5) & 7;
        const int cl   = bid >> 8;

        const float* __restrict__ P = cl ? gt : pred;
        float* __restrict__ dCol = densCol + (size_t)(cl*NB + b) * (TRIVEC*TS);
        float* __restrict__ dRow = densRow
            + (size_t)((half*4 + wave)*2 + cl) * PTSTOT + b * NPTS;
        const float bw = cl ? bwg[0] : bwp[0];
        const float sc = sqrtf(0.5f / (bw*bw*0.6931471805599453f)); // exp2 scale

        const int n0  = 32 - u;                // seg A step count (RT=u)
        const int lo  = half ? 17 : 0;
        const int hi  = half ? 33 : 17;
        const int nst = hi - lo;               // 17 or 16
        int nA = n0 - lo; if (nA < 0) nA = 0; if (nA > nst) nA = nst;
        const int tA0 = u + lo;                // seg A first col tile
        const int tB0 = 31 - u;                // seg B first col tile (diag)

        const float4* cb4 = (const float4*)(P + (size_t)b*NPTS*3);

        if (tid < 96) {
            float4 v = cb4[u*96 + tid];
            v.x*=sc; v.y*=sc; v.z*=sc; v.w*=sc;  sRowA[tid] = v;
        } else if (tid < 192) {
            float4 v = cb4[(31-u)*96 + (tid-96)];
            v.x*=sc; v.y*=sc; v.z*=sc; v.w*=sc;  sRowB[tid-96] = v;
        }
        const int nA96 = nA * 96;
        for (int i = tid; i < nst*96; i += TPB) {
            float4 v = (i < nA96) ? cb4[tA0*96 + i] : cb4[tB0*96 + (i - nA96)];
            v.x*=sc; v.y*=sc; v.z*=sc; v.w*=sc;  sCol[i] = v;
        }
        __syncthreads();

        float rx[8], ry[8], rz[8], nrr[8], racc[8];
        const bool startA = (lo < n0);
        unpack8(startA ? sRowA : sRowB, ty*6, rx, ry, rz);
        #pragma unroll
        for (int r = 0; r < 8; ++r) {
            nrr[r]  = -fmaf(rx[r],rx[r], fmaf(ry[r],ry[r], rz[r]*rz[r]));
            racc[r] = 0.0f;
        }
        int curRT = startA ? u : 31-u;

        auto flushRows = [&](int RTf) {       // per-wave partial, plain store
            #pragma unroll
            for (int r = 0; r < 8; ++r) {
                float v = racc[r];
                v += __shfl_xor(v, 16, 64);
                v += __shfl_xor(v, 32, 64);
                if ((tx & 3) == 0)
                    dRow[RTf*TS + ty*8 + r] = v;
            }
        };

        for (int s = lo; s < hi; ++s) {
            const int t     = s - lo;
            const bool segA = (s < n0);
            const int RT    = segA ? u : 31-u;
            const int TV    = segA ? u + s : (31-u) + (s - n0);

            if (RT != curRT) {          // at most once (u -> 31-u)
                flushRows(curRT);
                unpack8(sRowB, ty*6, rx, ry, rz);
                #pragma unroll
                for (int r = 0; r < 8; ++r) {
                    nrr[r]  = -fmaf(rx[r],rx[r], fmaf(ry[r],ry[r], rz[r]*rz[r]));
                    racc[r] = 0.0f;
                }
                curRT = RT;
            }

            float cx[8], cy[8], cz[8];
            unpack8(sCol, t*96 + tx*6, cx, cy, cz);

            if (s == 0 || s == n0) {
                // diagonal tile: rows only (self incl., exp2(0)=1)
                #pragma unroll
                for (int c = 0; c < 8; ++c) {
                    const float ax = 2.0f*cx[c], ay = 2.0f*cy[c], az = 2.0f*cz[c];
                    const float ncc = fmaf(-cx[c],cx[c],
                                      fmaf(-cy[c],cy[c], -cz[c]*cz[c]));
                    #pragma unroll
                    for (int r = 0; r < 8; ++r) {
                        float e = fmaf(ax, rx[r], ncc);
                        e = fmaf(ay, ry[r], e);
                        e = fmaf(az, rz[r], e);
                        racc[r] += __builtin_amdgcn_exp2f(e + nrr[r]);
                    }
                }
            } else {
                float cacc[8];
                #pragma unroll
                for (int c = 0; c < 8; ++c) cacc[c] = 0.0f;
                #pragma unroll
                for (int c = 0; c < 8; ++c) {
                    const float ax = 2.0f*cx[c], ay = 2.0f*cy[c], az = 2.0f*cz[c];
                    const float ncc = fmaf(-cx[c],cx[c],
                                      fmaf(-cy[c],cy[c], -cz[c]*cz[c]));
                    #pragma unroll
                    for (int r = 0; r < 8; ++r) {
                        float e = fmaf(ax, rx[r], ncc);
                        e = fmaf(ay, ry[r], e);
                        e = fmaf(az, rz[r], e);
                        const float k = __builtin_amdgcn_exp2f(e + nrr[r]);
                        racc[r] += k;
                        cacc[c] += k;
                    }
                }
                // col partial: complete over this strip's 128 rows, one store
                const int triTV = (TV*(TV-1)) >> 1;
                #pragma unroll
                for (int c = 0; c < 8; ++c) {
                    float v = cacc[c];
                    v += __shfl_xor(v, 1, 64);
                    v += __shfl_xor(v, 2, 64);
                    v += __shfl_xor(v, 4, 64);
                    v += __shfl_xor(v, 8, 64);
                    if (ty == 0)
                        dCol[(triTV + RT)*TS + tx*8 + c] = v;
                }
            }
        }
        flushRows(curRT);
    } else {
        // ============ cross: pred strip I x 16 gt tiles (one phase) ==========
        const int cb   = bid - DENS_BLKS;
        const int b    = cb >> 6;
        const int rest = cb & 63;
        const int I    = rest >> 1;
        const int ph   = rest & 1;

        const float4* pb4 = (const float4*)(pred + (size_t)b*NPTS*3);
        const float4* gb4 = (const float4*)(gt   + (size_t)b*NPTS*3);
        if (tid < 96) sRowA[tid] = pb4[I*96 + tid];
        #pragma unroll
        for (int i = 0; i < 6; ++i)
            sCol[tid + i*TPB] = gb4[ph*1536 + tid + i*TPB];
        __syncthreads();

        float rx[8], ry[8], rz[8], rr[8], rmin[8];
        unpack8(sRowA, ty*6, rx, ry, rz);
        #pragma unroll
        for (int r = 0; r < 8; ++r) {
            rr[r]   = fmaf(rx[r],rx[r], fmaf(ry[r],ry[r], rz[r]*rz[r]));
            rmin[r] = BIGF;
        }
        float* __restrict__ mg = minG2Pp + (size_t)I*PTSTOT + b*NPTS;

        for (int t = 0; t < 16; ++t) {
            float cx[8], cy[8], cz[8], cmin[8];
            unpack8(sCol, t*96 + tx*6, cx, cy, cz);
            #pragma unroll
            for (int c = 0; c < 8; ++c) cmin[c] = BIGF;
            #pragma unroll
            for (int c = 0; c < 8; ++c) {
                const float ax = -2.0f*cx[c], ay = -2.0f*cy[c], az = -2.0f*cz[c];
                const float cc = fmaf(cx[c],cx[c], fmaf(cy[c],cy[c], cz[c]*cz[c]));
                #pragma unroll
                for (int r = 0; r < 8; ++r) {
                    float tv = fmaf(ax, rx[r], cc);
                    tv = fmaf(ay, ry[r], tv);
                    tv = fmaf(az, rz[r], tv);
                    rmin[r] = fminf(rmin[r], tv);          // +rr at end
                    cmin[c] = fminf(cmin[c], tv + rr[r]);  // true d^2
                }
            }
            // col-min partial: complete over strip rows, exclusive plain store
            #pragma unroll
            for (int c = 0; c < 8; ++c) {
                float v = fmaxf(cmin[c], 0.0f);
                v = fminf(v, __shfl_xor(v, 1, 64));
                v = fminf(v, __shfl_xor(v, 2, 64));
                v = fminf(v, __shfl_xor(v, 4, 64));
                v = fminf(v, __shfl_xor(v, 8, 64));
                if (ty == 0)
                    mg[(ph*16+t)*TS + tx*8 + c] = v;
            }
        }
        // row-min per-wave partial, plain store
        float* __restrict__ mp = minP2Gp
            + (size_t)(ph*4 + wave)*PTSTOT + b*NPTS + I*TS;
        #pragma unroll
        for (int r = 0; r < 8; ++r) {
            float v = fmaxf(rmin[r] + rr[r], 0.0f);
            v = fminf(v, __shfl_xor(v, 16, 64));
            v = fminf(v, __shfl_xor(v, 32, 64));
            if ((tx & 3) == 0)
                mp[ty*8 + r] = v;
        }
    }
}

__global__ __launch_bounds__(256) void dacl_combine(
    const float* __restrict__ minP2Gp, const float* __restrict__ minG2Pp,
    const float* __restrict__ densCol, const float* __restrict__ densRow,
    float* __restrict__ bsum)
{
    const int g   = blockIdx.x * 256 + threadIdx.x;  // [0, 65536)
    const int dir = g >> 15;
    const int idx = g & 32767;
    const int b   = idx >> 12;
    const int pt  = idx & 4095;
    const int T   = pt >> 7;
    const int co  = pt & 127;
    const int cl  = dir;

    float m = BIGF;
    if (dir == 0) {
        #pragma unroll
        for (int s = 0; s < 8; ++s) m = fminf(m, minP2Gp[s*PTSTOT + idx]);
    } else {
        #pragma unroll
        for (int s = 0; s < 32; ++s) m = fminf(m, minG2Pp[s*PTSTOT + idx]);
    }

    float dn = 0.0f;
    const float* dC = densCol + (size_t)(cl*NB + b)*(TRIVEC*TS)
                      + ((T*(T-1)) >> 1)*TS + co;
    for (int RT = 0; RT < T; ++RT) dn += dC[RT*TS];     // col contributions
    #pragma unroll
    for (int hw = 0; hw < 8; ++hw) {                    // row contributions
        const bool valid = (hw < 4) ? (T < 16) : (T != 15);
        if (valid) dn += densRow[(size_t)(hw*2 + cl)*PTSTOT + idx];
    }

    float val = m / (dn * (1.0f/4095.0f) + 1e-6f) * (1.0f/32768.0f);

    #pragma unroll
    for (int off = 32; off; off >>= 1) val += __shfl_down(val, off);
    __shared__ float sm[4];
    const int lane = threadIdx.x & 63, wid = threadIdx.x >> 6;
    if (lane == 0) sm[wid] = val;
    __syncthreads();
    if (threadIdx.x == 0) bsum[blockIdx.x] = (sm[0] + sm[1]) + (sm[2] + sm[3]);
}

__global__ __launch_bounds__(256) void dacl_final(
    const float* __restrict__ bsum, float* __restrict__ out)
{
    float v = bsum[threadIdx.x];
    #pragma unroll
    for (int off = 32; off; off >>= 1) v += __shfl_down(v, off);
    __shared__ float sm[4];
    const int lane = threadIdx.x & 63, wid = threadIdx.x >> 6;
    if (lane == 0) sm[wid] = v;
    __syncthreads();
    if (threadIdx.x == 0) out[0] = (sm[0] + sm[1]) + (sm[2] + sm[3]);
}

extern "C" void kernel_launch(void* const* d_in, const int* in_sizes, int n_in,
                              void* d_out, int out_size, void* d_ws, size_t ws_size,
                              hipStream_t stream)
{
    const float* pred = (const float*)d_in[0];
    const float* gt   = (const float*)d_in[1];
    const float* bwp  = (const float*)d_in[2];
    const float* bwg  = (const float*)d_in[3];

    float* minP2Gp = (float*)d_ws;                      // [8][32768]   1 MB
    float* minG2Pp = minP2Gp + (size_t)8*PTSTOT;        // [32][32768]  4 MB
    float* densCol = minG2Pp + (size_t)32*PTSTOT;       // [16][496][128] 3.9 MB
    float* densRow = densCol + (size_t)16*TRIVEC*TS;    // [16][32768]  2 MB
    float* bsum    = densRow + (size_t)16*PTSTOT;       // [256]

    dacl_pairs<<<DENS_BLKS + CROSS_BLKS, TPB, 0, stream>>>(
        pred, gt, bwp, bwg, minP2Gp, minG2Pp, densCol, densRow);
    dacl_combine<<<256, 256, 0, stream>>>(minP2Gp, minG2Pp, densCol, densRow, bsum);
    dacl_final<<<1, 256, 0, stream>>>(bsum, (float*)d_out);
}

// Round 9
// 89.382 us; speedup vs baseline: 1.7268x; 1.0467x over previous
//
#include <hip/hip_runtime.h>

// Density-Aware Chamfer Loss, B=8, N=M=4096, fp32.
// Round 9: round-8 dedup math (zero atomics, exclusive partial arrays) with a
// 4x finer grid (4096 blocks, 12.3KB LDS) for occupancy/tail, seg-B staging
// fix, and cross-wave-gathered row-density partials (2MB, masked combine).

#define NPTS 4096
#define NB   8
#define TS   128
#define TPB  256
#define NT   32
#define BIGF 3.4e38f

#define DENS_BLKS  2048      // cl(2) * b(8) * u(16) * q(8)
#define CROSS_BLKS 2048      // b(8) * I(32) * ph(8)
#define PTSTOT (NB*NPTS)     // 32768
#define TRIVEC 496           // packed (RT<TV) tile pairs

// unpack 8 consecutive xyz points (6 float4) from LDS into register arrays
__device__ __forceinline__ void unpack8(const float4* s4, int base,
                                        float (&X)[8], float (&Y)[8], float (&Z)[8])
{
    float4 A = s4[base+0], B = s4[base+1], C = s4[base+2];
    float4 D = s4[base+3], E = s4[base+4], F = s4[base+5];
    X[0]=A.x; Y[0]=A.y; Z[0]=A.z;  X[1]=A.w; Y[1]=B.x; Z[1]=B.y;
    X[2]=B.z; Y[2]=B.w; Z[2]=C.x;  X[3]=C.y; Y[3]=C.z; Z[3]=C.w;
    X[4]=D.x; Y[4]=D.y; Z[4]=D.z;  X[5]=D.w; Y[5]=E.x; Z[5]=E.y;
    X[6]=E.z; Y[6]=E.w; Z[6]=F.x;  X[7]=F.y; Y[7]=F.z; Z[7]=F.w;
}

__global__ __launch_bounds__(TPB) void dacl_pairs(
    const float* __restrict__ pred, const float* __restrict__ gt,
    const float* __restrict__ bwp,  const float* __restrict__ bwg,
    float* __restrict__ minP2Gp,   // [8 ph][PTSTOT]
    float* __restrict__ minG2Pp,   // [32 I][PTSTOT]
    float* __restrict__ densCol,   // [(cl*8+b)][TRIVEC][TS]  (tri-packed)
    float* __restrict__ densRow)   // [8 q][2 cl][PTSTOT]   (masked in combine)
{
    __shared__ float4 sCol[480];       // 7.5 KB: up to 5 col tiles
    __shared__ float4 sRowA[96], sRowB[96];
    __shared__ float  sRed[384];       // cross-wave gather scratch

    const int tid  = threadIdx.x;
    const int ty   = tid & 15;         // row octet (lane bits 0..3)
    const int tx   = tid >> 4;         // col octet
    const int wave = tid >> 6;
    const int lane = tid & 63;
    const int bid  = blockIdx.x;

    if (bid < DENS_BLKS) {
        // ============ density: strip-pair {u, 31-u}, one col eighth ==========
        const int q  = bid & 7;
        const int u  = (bid >> 3) & 15;
        const int b  = (bid >> 7) & 7;
        const int cl = bid >> 10;

        const float* __restrict__ P = cl ? gt : pred;
        float* __restrict__ dCol = densCol + (size_t)(cl*NB + b) * (TRIVEC*TS);
        float* __restrict__ dRow = densRow + (size_t)(q*2 + cl) * PTSTOT + b*NPTS;
        const float bw = cl ? bwg[0] : bwp[0];
        const float sc = sqrtf(0.5f / (bw*bw*0.6931471805599453f)); // exp2 scale

        const int n0  = 32 - u;                // seg A step count (RT=u)
        const int lo  = (q*33) >> 3;
        const int hi  = ((q+1)*33) >> 3;
        const int nst = hi - lo;               // 4 or 5
        int nA = n0 - lo; if (nA < 0) nA = 0; if (nA > nst) nA = nst;
        const int tA0 = u + lo;                // seg A first col tile
        const int sB0 = lo > n0 ? lo : n0;
        const int tBs = (31 - u) + (sB0 - n0); // seg B first STAGED col tile

        const float4* cb4 = (const float4*)(P + (size_t)b*NPTS*3);

        if (tid < 96) {
            float4 v = cb4[u*96 + tid];
            v.x*=sc; v.y*=sc; v.z*=sc; v.w*=sc;  sRowA[tid] = v;
        } else if (tid < 192) {
            float4 v = cb4[(31-u)*96 + (tid-96)];
            v.x*=sc; v.y*=sc; v.z*=sc; v.w*=sc;  sRowB[tid-96] = v;
        }
        const int nA96 = nA * 96;
        for (int i = tid; i < nst*96; i += TPB) {
            float4 v = (i < nA96) ? cb4[tA0*96 + i] : cb4[tBs*96 + (i - nA96)];
            v.x*=sc; v.y*=sc; v.z*=sc; v.w*=sc;  sCol[i] = v;
        }
        __syncthreads();

        float rx[8], ry[8], rz[8], nrr[8], racc[8];
        const bool startA = (lo < n0);
        unpack8(startA ? sRowA : sRowB, ty*6, rx, ry, rz);
        #pragma unroll
        for (int r = 0; r < 8; ++r) {
            nrr[r]  = -fmaf(rx[r],rx[r], fmaf(ry[r],ry[r], rz[r]*rz[r]));
            racc[r] = 0.0f;
        }
        int curRT = startA ? u : 31-u;

        // uniform-condition flush: cross-wave gather, one plain store
        auto flushRows = [&](int RTf) {
            float vv[8];
            #pragma unroll
            for (int r = 0; r < 8; ++r) {
                float v = racc[r];
                v += __shfl_xor(v, 16, 64);
                v += __shfl_xor(v, 32, 64);
                vv[r] = v;
            }
            __syncthreads();
            if (wave > 0 && lane < 16) {
                #pragma unroll
                for (int r = 0; r < 8; ++r)
                    sRed[(wave-1)*128 + lane*8 + r] = vv[r];
            }
            __syncthreads();
            if (wave == 0 && lane < 16) {
                #pragma unroll
                for (int r = 0; r < 8; ++r) {
                    const int o = lane*8 + r;
                    dRow[RTf*TS + o] = (vv[r] + sRed[o])
                                     + (sRed[128+o] + sRed[256+o]);
                }
            }
        };

        for (int s = lo; s < hi; ++s) {
            const int t     = s - lo;
            const bool segA = (s < n0);
            const int RT    = segA ? u : 31-u;
            const int TV    = segA ? u + s : (31-u) + (s - n0);

            if (RT != curRT) {          // at most once (u -> 31-u), uniform
                flushRows(curRT);
                unpack8(sRowB, ty*6, rx, ry, rz);
                #pragma unroll
                for (int r = 0; r < 8; ++r) {
                    nrr[r]  = -fmaf(rx[r],rx[r], fmaf(ry[r],ry[r], rz[r]*rz[r]));
                    racc[r] = 0.0f;
                }
                curRT = RT;
            }

            float cx[8], cy[8], cz[8];
            unpack8(sCol, t*96 + tx*6, cx, cy, cz);

            if (s == 0 || s == n0) {
                // diagonal tile: rows only (self incl., exp2(0)=1)
                #pragma unroll
                for (int c = 0; c < 8; ++c) {
                    const float ax = 2.0f*cx[c], ay = 2.0f*cy[c], az = 2.0f*cz[c];
                    const float ncc = fmaf(-cx[c],cx[c],
                                      fmaf(-cy[c],cy[c], -cz[c]*cz[c]));
                    #pragma unroll
                    for (int r = 0; r < 8; ++r) {
                        float e = fmaf(ax, rx[r], ncc);
                        e = fmaf(ay, ry[r], e);
                        e = fmaf(az, rz[r], e);
                        racc[r] += __builtin_amdgcn_exp2f(e + nrr[r]);
                    }
                }
            } else {
                float cacc[8];
                #pragma unroll
                for (int c = 0; c < 8; ++c) cacc[c] = 0.0f;
                #pragma unroll
                for (int c = 0; c < 8; ++c) {
                    const float ax = 2.0f*cx[c], ay = 2.0f*cy[c], az = 2.0f*cz[c];
                    const float ncc = fmaf(-cx[c],cx[c],
                                      fmaf(-cy[c],cy[c], -cz[c]*cz[c]));
                    #pragma unroll
                    for (int r = 0; r < 8; ++r) {
                        float e = fmaf(ax, rx[r], ncc);
                        e = fmaf(ay, ry[r], e);
                        e = fmaf(az, rz[r], e);
                        const float k = __builtin_amdgcn_exp2f(e + nrr[r]);
                        racc[r] += k;
                        cacc[c] += k;
                    }
                }
                // col partial: complete over this strip's 128 rows, one store
                const int triTV = (TV*(TV-1)) >> 1;
                #pragma unroll
                for (int c = 0; c < 8; ++c) {
                    float v = cacc[c];
                    v += __shfl_xor(v, 1, 64);
                    v += __shfl_xor(v, 2, 64);
                    v += __shfl_xor(v, 4, 64);
                    v += __shfl_xor(v, 8, 64);
                    if (ty == 0)
                        dCol[(triTV + RT)*TS + tx*8 + c] = v;
                }
            }
        }
        flushRows(curRT);
    } else {
        // ============ cross: pred strip I x 4 gt tiles (one phase) ===========
        const int cb = bid - DENS_BLKS;
        const int b  = cb >> 8;
        const int I  = (cb >> 3) & 31;
        const int ph = cb & 7;

        const float4* pb4 = (const float4*)(pred + (size_t)b*NPTS*3);
        const float4* gb4 = (const float4*)(gt   + (size_t)b*NPTS*3);
        if (tid < 96) sRowA[tid] = pb4[I*96 + tid];
        #pragma unroll
        for (int i = 0; i < 2; ++i) {
            const int o = tid + i*TPB;
            if (o < 384) sCol[o] = gb4[ph*384 + o];
        }
        __syncthreads();

        float rx[8], ry[8], rz[8], rr[8], rmin[8];
        unpack8(sRowA, ty*6, rx, ry, rz);
        #pragma unroll
        for (int r = 0; r < 8; ++r) {
            rr[r]   = fmaf(rx[r],rx[r], fmaf(ry[r],ry[r], rz[r]*rz[r]));
            rmin[r] = BIGF;
        }
        float* __restrict__ mg = minG2Pp + (size_t)I*PTSTOT + b*NPTS;

        for (int t = 0; t < 4; ++t) {
            float cx[8], cy[8], cz[8], cmin[8];
            unpack8(sCol, t*96 + tx*6, cx, cy, cz);
            #pragma unroll
            for (int c = 0; c < 8; ++c) cmin[c] = BIGF;
            #pragma unroll
            for (int c = 0; c < 8; ++c) {
                const float ax = -2.0f*cx[c], ay = -2.0f*cy[c], az = -2.0f*cz[c];
                const float cc = fmaf(cx[c],cx[c], fmaf(cy[c],cy[c], cz[c]*cz[c]));
                #pragma unroll
                for (int r = 0; r < 8; ++r) {
                    float tv = fmaf(ax, rx[r], cc);
                    tv = fmaf(ay, ry[r], tv);
                    tv = fmaf(az, rz[r], tv);
                    rmin[r] = fminf(rmin[r], tv);          // +rr at end
                    cmin[c] = fminf(cmin[c], tv + rr[r]);  // true d^2
                }
            }
            // col-min partial: complete over strip rows, exclusive plain store
            #pragma unroll
            for (int c = 0; c < 8; ++c) {
                float v = fmaxf(cmin[c], 0.0f);
                v = fminf(v, __shfl_xor(v, 1, 64));
                v = fminf(v, __shfl_xor(v, 2, 64));
                v = fminf(v, __shfl_xor(v, 4, 64));
                v = fminf(v, __shfl_xor(v, 8, 64));
                if (ty == 0)
                    mg[(ph*4+t)*TS + tx*8 + c] = v;
            }
        }
        // row-min: cross-wave gather, one plain store per phase
        float vv[8];
        #pragma unroll
        for (int r = 0; r < 8; ++r) {
            float v = fmaxf(rmin[r] + rr[r], 0.0f);
            v = fminf(v, __shfl_xor(v, 16, 64));
            v = fminf(v, __shfl_xor(v, 32, 64));
            vv[r] = v;
        }
        __syncthreads();
        if (wave > 0 && lane < 16) {
            #pragma unroll
            for (int r = 0; r < 8; ++r) sRed[(wave-1)*128 + lane*8 + r] = vv[r];
        }
        __syncthreads();
        if (wave == 0 && lane < 16) {
            #pragma unroll
            for (int r = 0; r < 8; ++r) {
                const int o = lane*8 + r;
                minP2Gp[(size_t)ph*PTSTOT + b*NPTS + I*TS + o] =
                    fminf(fminf(vv[r], sRed[o]),
                          fminf(sRed[128+o], sRed[256+o]));
            }
        }
    }
}

__global__ __launch_bounds__(256) void dacl_combine(
    const float* __restrict__ minP2Gp, const float* __restrict__ minG2Pp,
    const float* __restrict__ densCol, const float* __restrict__ densRow,
    float* __restrict__ bsum)
{
    const int g   = blockIdx.x * 256 + threadIdx.x;  // [0, 65536)
    const int dir = g >> 15;
    const int idx = g & 32767;
    const int b   = idx >> 12;
    const int pt  = idx & 4095;
    const int T   = pt >> 7;
    const int co  = pt & 127;
    const int cl  = dir;

    float m = BIGF;
    if (dir == 0) {
        #pragma unroll
        for (int s = 0; s < 8; ++s) m = fminf(m, minP2Gp[(size_t)s*PTSTOT + idx]);
    } else {
        #pragma unroll
        for (int s = 0; s < 32; ++s) m = fminf(m, minG2Pp[(size_t)s*PTSTOT + idx]);
    }

    float dn = 0.0f;
    const float* dC = densCol + (size_t)(cl*NB + b)*(TRIVEC*TS)
                      + ((T*(T-1)) >> 1)*TS + co;
    for (int RT = 0; RT < T; ++RT) dn += dC[RT*TS];     // col contributions
    #pragma unroll
    for (int q = 0; q < 8; ++q) {                       // row contributions
        const int lo = (q*33) >> 3, hi = ((q+1)*33) >> 3;
        const bool valid = (T < 16) ? (lo < 32 - T) : (hi > T + 1);
        if (valid) dn += densRow[(size_t)(q*2 + cl)*PTSTOT + idx];
    }

    float val = m / (dn * (1.0f/4095.0f) + 1e-6f) * (1.0f/32768.0f);

    #pragma unroll
    for (int off = 32; off; off >>= 1) val += __shfl_down(val, off);
    __shared__ float sm[4];
    const int lane = threadIdx.x & 63, wid = threadIdx.x >> 6;
    if (lane == 0) sm[wid] = val;
    __syncthreads();
    if (threadIdx.x == 0) bsum[blockIdx.x] = (sm[0] + sm[1]) + (sm[2] + sm[3]);
}

__global__ __launch_bounds__(256) void dacl_final(
    const float* __restrict__ bsum, float* __restrict__ out)
{
    float v = bsum[threadIdx.x];
    #pragma unroll
    for (int off = 32; off; off >>= 1) v += __shfl_down(v, off);
    __shared__ float sm[4];
    const int lane = threadIdx.x & 63, wid = threadIdx.x >> 6;
    if (lane == 0) sm[wid] = v;
    __syncthreads();
    if (threadIdx.x == 0) out[0] = (sm[0] + sm[1]) + (sm[2] + sm[3]);
}

extern "C" void kernel_launch(void* const* d_in, const int* in_sizes, int n_in,
                              void* d_out, int out_size, void* d_ws, size_t ws_size,
                              hipStream_t stream)
{
    const float* pred = (const float*)d_in[0];
    const float* gt   = (const float*)d_in[1];
    const float* bwp  = (const float*)d_in[2];
    const float* bwg  = (const float*)d_in[3];

    float* minP2Gp = (float*)d_ws;                      // [8][32768]     1 MB
    float* minG2Pp = minP2Gp + (size_t)8*PTSTOT;        // [32][32768]    4 MB
    float* densCol = minG2Pp + (size_t)32*PTSTOT;       // [16][496][128] 3.9 MB
    float* densRow = densCol + (size_t)16*TRIVEC*TS;    // [16][32768]    2 MB
    float* bsum    = densRow + (size_t)16*PTSTOT;       // [256]

    dacl_pairs<<<DENS_BLKS + CROSS_BLKS, TPB, 0, stream>>>(
        pred, gt, bwp, bwg, minP2Gp, minG2Pp, densCol, densRow);
    dacl_combine<<<256, 256, 0, stream>>>(minP2Gp, minG2Pp, densCol, densRow, bsum);
    dacl_final<<<1, 256, 0, stream>>>(bsum, (float*)d_out);
}

// Round 10
// 88.864 us; speedup vs baseline: 1.7369x; 1.0058x over previous
//
#include <hip/hip_runtime.h>

// Density-Aware Chamfer Loss, B=8, N=M=4096, fp32.
// Round 10: zero-atomic dedup (r8/r9) + flattened control flow:
//  - density: one block = one row strip u x <=4 contiguous col tiles (uniform
//    chunk), single register accumulator, one flush, no dynamic strip switch.
//  - cross: 2x2 microblock min-tree (v_min3 fusion), clamps moved to combine.

#define NPTS 4096
#define NB   8
#define TS   128
#define TPB  256
#define NT   32
#define BIGF 3.4e38f

#define DCHUNKS    144               // sum_u ceil((32-u)/4)
#define DENS_BLKS  (16*DCHUNKS)      // cl(2) * b(8) * 144 = 2304
#define CROSS_BLKS 2048              // b(8) * I(32) * ph(8)
#define PTSTOT (NB*NPTS)             // 32768
#define TRIVEC 496                   // packed (RT<TV) tile pairs

// unpack 8 consecutive xyz points (6 float4) from LDS into register arrays
__device__ __forceinline__ void unpack8(const float4* s4, int base,
                                        float (&X)[8], float (&Y)[8], float (&Z)[8])
{
    float4 A = s4[base+0], B = s4[base+1], C = s4[base+2];
    float4 D = s4[base+3], E = s4[base+4], F = s4[base+5];
    X[0]=A.x; Y[0]=A.y; Z[0]=A.z;  X[1]=A.w; Y[1]=B.x; Z[1]=B.y;
    X[2]=B.z; Y[2]=B.w; Z[2]=C.x;  X[3]=C.y; Y[3]=C.z; Z[3]=C.w;
    X[4]=D.x; Y[4]=D.y; Z[4]=D.z;  X[5]=D.w; Y[5]=E.x; Z[5]=E.y;
    X[6]=E.z; Y[6]=E.w; Z[6]=F.x;  X[7]=F.y; Y[7]=F.z; Z[7]=F.w;
}

__global__ __launch_bounds__(TPB) void dacl_pairs(
    const float* __restrict__ pred, const float* __restrict__ gt,
    const float* __restrict__ bwp,  const float* __restrict__ bwg,
    float* __restrict__ minP2Gp,   // [8 ph][PTSTOT]
    float* __restrict__ minG2Pp,   // [32 I][PTSTOT]
    float* __restrict__ densCol,   // [(cl*8+b)][TRIVEC][TS]  (tri-packed)
    float* __restrict__ densRow)   // [8 cj][2 cl][PTSTOT]   (masked in combine)
{
    __shared__ float4 sCol[384];       // 6 KB: up to 4 col tiles
    __shared__ float4 sRow[96];        // 1.5 KB
    __shared__ float  sRed[384];       // cross-wave gather scratch

    const int tid  = threadIdx.x;
    const int ty   = tid & 15;         // row octet (lane bits 0..3)
    const int tx   = tid >> 4;         // col octet
    const int wave = tid >> 6;
    const int lane = tid & 63;
    const int bid  = blockIdx.x;

    if (bid < DENS_BLKS) {
        // ============ density: strip u x chunk of <=4 col tiles ==============
        const int cb = bid / DCHUNKS;       // (cl*8 + b)
        int rem      = bid - cb * DCHUNKS;  // chunk id within (cl,b)
        const int b  = cb & 7;
        const int cl = cb >> 3;

        int u = 0;                          // find strip u and chunk index cj
        int nc = 8;                         // (35-0)>>2
        while (rem >= nc) { rem -= nc; ++u; nc = (35 - u) >> 2; }
        const int cj = rem;
        const int js = cj * 4;
        const int steps = 32 - u;
        const int je = (js + 4 < steps) ? js + 4 : steps;
        const int nT = je - js;             // 1..4 staged col tiles

        const float* __restrict__ P = cl ? gt : pred;
        float* __restrict__ dCol = densCol + (size_t)(cl*NB + b) * (TRIVEC*TS);
        float* __restrict__ dRow = densRow + (size_t)(cj*2 + cl) * PTSTOT + b*NPTS;
        const float bw = cl ? bwg[0] : bwp[0];
        const float sc = sqrtf(0.5f / (bw*bw*0.6931471805599453f)); // exp2 scale

        const float4* cb4 = (const float4*)(P + (size_t)b*NPTS*3);

        if (tid < 96) {
            float4 v = cb4[u*96 + tid];
            v.x*=sc; v.y*=sc; v.z*=sc; v.w*=sc;  sRow[tid] = v;
        }
        for (int i = tid; i < nT*96; i += TPB) {
            float4 v = cb4[(u + js)*96 + i];
            v.x*=sc; v.y*=sc; v.z*=sc; v.w*=sc;  sCol[i] = v;
        }
        __syncthreads();

        float rx[8], ry[8], rz[8], nrr[8], racc[8];
        unpack8(sRow, ty*6, rx, ry, rz);
        #pragma unroll
        for (int r = 0; r < 8; ++r) {
            nrr[r]  = -fmaf(rx[r],rx[r], fmaf(ry[r],ry[r], rz[r]*rz[r]));
            racc[r] = 0.0f;
        }

        for (int j = js; j < je; ++j) {
            const int t  = j - js;
            const int TV = u + j;

            float cx[8], cy[8], cz[8];
            unpack8(sCol, t*96 + tx*6, cx, cy, cz);

            if (j == 0) {
                // diagonal tile: rows only (self incl., exp2(0)=1)
                #pragma unroll
                for (int c = 0; c < 8; ++c) {
                    const float ax = 2.0f*cx[c], ay = 2.0f*cy[c], az = 2.0f*cz[c];
                    const float ncc = fmaf(-cx[c],cx[c],
                                      fmaf(-cy[c],cy[c], -cz[c]*cz[c]));
                    #pragma unroll
                    for (int r = 0; r < 8; ++r) {
                        float e = fmaf(ax, rx[r], ncc);
                        e = fmaf(ay, ry[r], e);
                        e = fmaf(az, rz[r], e);
                        racc[r] += __builtin_amdgcn_exp2f(e + nrr[r]);
                    }
                }
            } else {
                float cacc[8];
                #pragma unroll
                for (int c = 0; c < 8; ++c) cacc[c] = 0.0f;
                #pragma unroll
                for (int c = 0; c < 8; ++c) {
                    const float ax = 2.0f*cx[c], ay = 2.0f*cy[c], az = 2.0f*cz[c];
                    const float ncc = fmaf(-cx[c],cx[c],
                                      fmaf(-cy[c],cy[c], -cz[c]*cz[c]));
                    #pragma unroll
                    for (int r = 0; r < 8; ++r) {
                        float e = fmaf(ax, rx[r], ncc);
                        e = fmaf(ay, ry[r], e);
                        e = fmaf(az, rz[r], e);
                        const float k = __builtin_amdgcn_exp2f(e + nrr[r]);
                        racc[r] += k;
                        cacc[c] += k;
                    }
                }
                // col partial: complete over this strip's 128 rows, one store
                const int triTV = (TV*(TV-1)) >> 1;
                #pragma unroll
                for (int c = 0; c < 8; ++c) {
                    float v = cacc[c];
                    v += __shfl_xor(v, 1, 64);
                    v += __shfl_xor(v, 2, 64);
                    v += __shfl_xor(v, 4, 64);
                    v += __shfl_xor(v, 8, 64);
                    if (ty == 0)
                        dCol[(triTV + u)*TS + tx*8 + c] = v;
                }
            }
        }
        // row flush: cross-wave gather, one plain store
        {
            float vv[8];
            #pragma unroll
            for (int r = 0; r < 8; ++r) {
                float v = racc[r];
                v += __shfl_xor(v, 16, 64);
                v += __shfl_xor(v, 32, 64);
                vv[r] = v;
            }
            __syncthreads();
            if (wave > 0 && lane < 16) {
                #pragma unroll
                for (int r = 0; r < 8; ++r)
                    sRed[(wave-1)*128 + lane*8 + r] = vv[r];
            }
            __syncthreads();
            if (wave == 0 && lane < 16) {
                #pragma unroll
                for (int r = 0; r < 8; ++r) {
                    const int o = lane*8 + r;
                    dRow[u*TS + o] = (vv[r] + sRed[o])
                                   + (sRed[128+o] + sRed[256+o]);
                }
            }
        }
    } else {
        // ============ cross: pred strip I x 4 gt tiles (one phase) ===========
        const int cb = bid - DENS_BLKS;
        const int b  = cb >> 8;
        const int I  = (cb >> 3) & 31;
        const int ph = cb & 7;

        const float4* pb4 = (const float4*)(pred + (size_t)b*NPTS*3);
        const float4* gb4 = (const float4*)(gt   + (size_t)b*NPTS*3);
        if (tid < 96) sRow[tid] = pb4[I*96 + tid];
        #pragma unroll
        for (int i = 0; i < 2; ++i) {
            const int o = tid + i*TPB;
            if (o < 384) sCol[o] = gb4[ph*384 + o];
        }
        __syncthreads();

        float rx[8], ry[8], rz[8], rr[8], rmin[8];
        unpack8(sRow, ty*6, rx, ry, rz);
        #pragma unroll
        for (int r = 0; r < 8; ++r) {
            rr[r]   = fmaf(rx[r],rx[r], fmaf(ry[r],ry[r], rz[r]*rz[r]));
            rmin[r] = BIGF;
        }
        float* __restrict__ mg = minG2Pp + (size_t)I*PTSTOT + b*NPTS;

        for (int t = 0; t < 4; ++t) {
            float cx[8], cy[8], cz[8], cmin[8];
            unpack8(sCol, t*96 + tx*6, cx, cy, cz);
            #pragma unroll
            for (int c = 0; c < 8; ++c) cmin[c] = BIGF;
            #pragma unroll
            for (int c2 = 0; c2 < 4; ++c2) {
                const int c0 = 2*c2, c1 = c0 + 1;
                const float ax0 = -2.0f*cx[c0], ay0 = -2.0f*cy[c0], az0 = -2.0f*cz[c0];
                const float cc0 = fmaf(cx[c0],cx[c0], fmaf(cy[c0],cy[c0], cz[c0]*cz[c0]));
                const float ax1 = -2.0f*cx[c1], ay1 = -2.0f*cy[c1], az1 = -2.0f*cz[c1];
                const float cc1 = fmaf(cx[c1],cx[c1], fmaf(cy[c1],cy[c1], cz[c1]*cz[c1]));
                #pragma unroll
                for (int r2 = 0; r2 < 4; ++r2) {
                    const int r0 = 2*r2, r1 = r0 + 1;
                    float t00 = fmaf(ax0, rx[r0], cc0);
                    t00 = fmaf(ay0, ry[r0], t00); t00 = fmaf(az0, rz[r0], t00);
                    float t01 = fmaf(ax1, rx[r0], cc1);
                    t01 = fmaf(ay1, ry[r0], t01); t01 = fmaf(az1, rz[r0], t01);
                    float t10 = fmaf(ax0, rx[r1], cc0);
                    t10 = fmaf(ay0, ry[r1], t10); t10 = fmaf(az0, rz[r1], t10);
                    float t11 = fmaf(ax1, rx[r1], cc1);
                    t11 = fmaf(ay1, ry[r1], t11); t11 = fmaf(az1, rz[r1], t11);
                    // row mins (rr folded out; min3-fusable trees)
                    rmin[r0] = fminf(rmin[r0], fminf(t00, t01));
                    rmin[r1] = fminf(rmin[r1], fminf(t10, t11));
                    // col mins need true d^2
                    const float d00 = t00 + rr[r0], d01 = t01 + rr[r0];
                    const float d10 = t10 + rr[r1], d11 = t11 + rr[r1];
                    cmin[c0] = fminf(cmin[c0], fminf(d00, d10));
                    cmin[c1] = fminf(cmin[c1], fminf(d01, d11));
                }
            }
            // col-min partial: complete over strip rows, exclusive plain store
            #pragma unroll
            for (int c = 0; c < 8; ++c) {
                float v = cmin[c];
                v = fminf(v, __shfl_xor(v, 1, 64));
                v = fminf(v, __shfl_xor(v, 2, 64));
                v = fminf(v, __shfl_xor(v, 4, 64));
                v = fminf(v, __shfl_xor(v, 8, 64));
                if (ty == 0)
                    mg[(ph*4+t)*TS + tx*8 + c] = v;
            }
        }
        // row-min: cross-wave gather, one plain store per phase
        float vv[8];
        #pragma unroll
        for (int r = 0; r < 8; ++r) {
            float v = rmin[r] + rr[r];
            v = fminf(v, __shfl_xor(v, 16, 64));
            v = fminf(v, __shfl_xor(v, 32, 64));
            vv[r] = v;
        }
        __syncthreads();
        if (wave > 0 && lane < 16) {
            #pragma unroll
            for (int r = 0; r < 8; ++r) sRed[(wave-1)*128 + lane*8 + r] = vv[r];
        }
        __syncthreads();
        if (wave == 0 && lane < 16) {
            #pragma unroll
            for (int r = 0; r < 8; ++r) {
                const int o = lane*8 + r;
                minP2Gp[(size_t)ph*PTSTOT + b*NPTS + I*TS + o] =
                    fminf(fminf(vv[r], sRed[o]),
                          fminf(sRed[128+o], sRed[256+o]));
            }
        }
    }
}

__global__ __launch_bounds__(256) void dacl_combine(
    const float* __restrict__ minP2Gp, const float* __restrict__ minG2Pp,
    const float* __restrict__ densCol, const float* __restrict__ densRow,
    float* __restrict__ bsum)
{
    const int g   = blockIdx.x * 256 + threadIdx.x;  // [0, 65536)
    const int dir = g >> 15;
    const int idx = g & 32767;
    const int b   = idx >> 12;
    const int pt  = idx & 4095;
    const int T   = pt >> 7;
    const int co  = pt & 127;
    const int cl  = dir;

    float m = BIGF;
    if (dir == 0) {
        #pragma unroll
        for (int s = 0; s < 8; ++s) m = fminf(m, minP2Gp[(size_t)s*PTSTOT + idx]);
    } else {
        #pragma unroll
        for (int s = 0; s < 32; ++s) m = fminf(m, minG2Pp[(size_t)s*PTSTOT + idx]);
    }
    m = fmaxf(m, 0.0f);

    float dn = 0.0f;
    const float* dC = densCol + (size_t)(cl*NB + b)*(TRIVEC*TS)
                      + ((T*(T-1)) >> 1)*TS + co;
    for (int RT = 0; RT < T; ++RT) dn += dC[RT*TS];     // col contributions
    const int ncj = (35 - T) >> 2;                      // chunks in strip T
    #pragma unroll
    for (int cj = 0; cj < 8; ++cj) {                    // row contributions
        if (cj < ncj) dn += densRow[(size_t)(cj*2 + cl)*PTSTOT + idx];
    }

    float val = m / (dn * (1.0f/4095.0f) + 1e-6f) * (1.0f/32768.0f);

    #pragma unroll
    for (int off = 32; off; off >>= 1) val += __shfl_down(val, off);
    __shared__ float sm[4];
    const int lane = threadIdx.x & 63, wid = threadIdx.x >> 6;
    if (lane == 0) sm[wid] = val;
    __syncthreads();
    if (threadIdx.x == 0) bsum[blockIdx.x] = (sm[0] + sm[1]) + (sm[2] + sm[3]);
}

__global__ __launch_bounds__(256) void dacl_final(
    const float* __restrict__ bsum, float* __restrict__ out)
{
    float v = bsum[threadIdx.x];
    #pragma unroll
    for (int off = 32; off; off >>= 1) v += __shfl_down(v, off);
    __shared__ float sm[4];
    const int lane = threadIdx.x & 63, wid = threadIdx.x >> 6;
    if (lane == 0) sm[wid] = v;
    __syncthreads();
    if (threadIdx.x == 0) out[0] = (sm[0] + sm[1]) + (sm[2] + sm[3]);
}

extern "C" void kernel_launch(void* const* d_in, const int* in_sizes, int n_in,
                              void* d_out, int out_size, void* d_ws, size_t ws_size,
                              hipStream_t stream)
{
    const float* pred = (const float*)d_in[0];
    const float* gt   = (const float*)d_in[1];
    const float* bwp  = (const float*)d_in[2];
    const float* bwg  = (const float*)d_in[3];

    float* minP2Gp = (float*)d_ws;                      // [8][32768]     1 MB
    float* minG2Pp = minP2Gp + (size_t)8*PTSTOT;        // [32][32768]    4 MB
    float* densCol = minG2Pp + (size_t)32*PTSTOT;       // [16][496][128] 3.9 MB
    float* densRow = densCol + (size_t)16*TRIVEC*TS;    // [16][32768]    2 MB
    float* bsum    = densRow + (size_t)16*PTSTOT;       // [256]

    dacl_pairs<<<DENS_BLKS + CROSS_BLKS, TPB, 0, stream>>>(
        pred, gt, bwp, bwg, minP2Gp, minG2Pp, densCol, densRow);
    dacl_combine<<<256, 256, 0, stream>>>(minP2Gp, minG2Pp, densCol, densRow, bsum);
    dacl_final<<<1, 256, 0, stream>>>(bsum, (float*)d_out);
}